// Round 1
// baseline (218.781 us; speedup 1.0000x reference)
//
#include <hip/hip_runtime.h>
#include <hip/hip_bf16.h>

// Attention: B=4, S=4096, D=64, fp32 in/out, causal + additive padding mask.
// Flash-attention: bf16 MFMA (16x16x32) for QK^T and PV, fp32 online softmax.

#define S_LEN 4096
#define D_K   64
#define N_B   4
#define QT    64          // q rows per workgroup
#define KVT   32          // kv columns per iteration
#define BIGNEG 1.25e9f    // INF / sqrt(64)

typedef __attribute__((ext_vector_type(8))) short short8;
typedef __attribute__((ext_vector_type(4))) float f32x4;

__device__ __forceinline__ unsigned short f2bf(float f) {
    union { float f; unsigned u; } v; v.f = f;
    unsigned r = v.u + 0x7FFF + ((v.u >> 16) & 1);   // round-to-nearest-even
    return (unsigned short)(r >> 16);
}

__global__ __launch_bounds__(256)
void attn_fwd(const float* __restrict__ Q, const float* __restrict__ K,
              const float* __restrict__ V, const float* __restrict__ M,
              float* __restrict__ O)
{
    const int tile  = blockIdx.x;          // 0..S/QT-1
    const int b     = blockIdx.y;          // batch
    const int qbase = tile * QT;
    const int tid   = threadIdx.x;
    const int wave  = tid >> 6;
    const int lane  = tid & 63;
    const int l15   = lane & 15;
    const int g     = lane >> 4;           // 0..3

    // K tile [32][64] bf16, XOR-swizzled 16B chunks (row stride 128B)
    __shared__ __attribute__((aligned(16))) unsigned short Klds[32 * 64];
    // V^T tile [64 d][40 k] bf16 (pad 32->40, row stride 80B: bank-spread, 16B-aligned)
    __shared__ __attribute__((aligned(16))) unsigned short Vtlds[64 * 40];
    // P per wave [16 q][40 k] bf16
    __shared__ __attribute__((aligned(16))) unsigned short Plds[4][16 * 40];

    const float* Qb = Q + ((size_t)b * S_LEN + qbase) * D_K;
    const float* Kb = K + (size_t)b * S_LEN * D_K;
    const float* Vb = V + (size_t)b * S_LEN * D_K;
    const float* Mb = M + (size_t)b * S_LEN;

    // ---- Q fragments (A-layout: m = lane&15, k = g*8+j), scale folded in ----
    const int qrow = 16 * wave + l15;      // row within tile
    short8 qf[2];
    #pragma unroll
    for (int dc = 0; dc < 2; ++dc) {
        const float* src = Qb + (size_t)qrow * D_K + dc * 32 + g * 8;
        #pragma unroll
        for (int j = 0; j < 8; ++j) qf[dc][j] = (short)f2bf(src[j] * 0.125f);
    }

    f32x4 acc[4];                          // O accum: acc[dtile][reg]; rows m=4g+r, cols d=dt*16+l15
    #pragma unroll
    for (int dt = 0; dt < 4; ++dt) acc[dt] = (f32x4){0.f, 0.f, 0.f, 0.f};
    float mrow[4], lrow[4];
    #pragma unroll
    for (int r = 0; r < 4; ++r) { mrow[r] = -1e30f; lrow[r] = 0.f; }

    const int q_max_wave = qbase + 16 * wave + 15;
    const int nkv = (qbase + QT) / KVT;    // causal: kv tiles with base <= last q row

    for (int it = 0; it < nkv; ++it) {
        const int kv = it * KVT;
        __syncthreads();                   // protect LDS from prev iteration's readers

        // ---- stage K tile: thread t -> row k=t>>3, 16B chunk c=t&7 (coalesced 32B reads)
        {
            const int k = tid >> 3, c = tid & 7;
            const float* src = Kb + (size_t)(kv + k) * D_K + c * 8;
            short8 t8;
            #pragma unroll
            for (int j = 0; j < 8; ++j) t8[j] = (short)f2bf(src[j]);
            const int byte = k * 128 + ((c * 16) ^ ((k & 7) << 4));
            *(short8*)((char*)Klds + byte) = t8;
        }
        // ---- stage V^T: thread t -> k = t&31, d-chunk = t>>5; scatter b16 writes
        {
            const int k = tid & 31, dch = tid >> 5;
            const float* src = Vb + (size_t)(kv + k) * D_K + dch * 8;
            #pragma unroll
            for (int j = 0; j < 8; ++j)
                Vtlds[(dch * 8 + j) * 40 + k] = f2bf(src[j]);
        }
        __syncthreads();

        if (kv > q_max_wave) continue;     // tile fully causally masked for this wave

        // ---- S = (Q/8)·K^T  (D-layout: q = 4g+r, k = 16*kt + l15) ----
        f32x4 s[2];
        s[0] = (f32x4){0.f,0.f,0.f,0.f};
        s[1] = (f32x4){0.f,0.f,0.f,0.f};
        #pragma unroll
        for (int kt = 0; kt < 2; ++kt) {
            const int krow = 16 * kt + l15;
            #pragma unroll
            for (int dc = 0; dc < 2; ++dc) {
                const int byte = krow * 128 + ((dc * 64 + g * 16) ^ ((krow & 7) << 4));
                short8 kf = *(const short8*)((const char*)Klds + byte);
                s[kt] = __builtin_amdgcn_mfma_f32_16x16x32_bf16(qf[dc], kf, s[kt], 0, 0, 0);
            }
        }

        // ---- masks: causal + additive padding (post-scale => subtract INF/8) ----
        float mk0 = Mb[kv + l15];
        float mk1 = Mb[kv + 16 + l15];
        #pragma unroll
        for (int kt = 0; kt < 2; ++kt) {
            const int gk = kv + 16 * kt + l15;
            const float madd = (1.0f - (kt ? mk1 : mk0)) * BIGNEG;
            #pragma unroll
            for (int r = 0; r < 4; ++r) {
                const int gq = qbase + 16 * wave + 4 * g + r;
                float v = s[kt][r] - madd;
                if (gk > gq) v -= BIGNEG;
                s[kt][r] = v;
            }
        }

        // ---- online softmax per row (row data: 16 lanes of this g-group) ----
        float pexp[2][4], alpha[4];
        #pragma unroll
        for (int r = 0; r < 4; ++r) {
            float tm = fmaxf(s[0][r], s[1][r]);
            #pragma unroll
            for (int off = 8; off >= 1; off >>= 1)
                tm = fmaxf(tm, __shfl_xor(tm, off, 64));
            const float mnew = fmaxf(mrow[r], tm);
            const float a  = __expf(mrow[r] - mnew);
            const float p0 = __expf(s[0][r] - mnew);
            const float p1 = __expf(s[1][r] - mnew);
            float rs = p0 + p1;
            #pragma unroll
            for (int off = 8; off >= 1; off >>= 1)
                rs += __shfl_xor(rs, off, 64);
            lrow[r] = lrow[r] * a + rs;
            mrow[r] = mnew;
            alpha[r] = a;
            pexp[0][r] = p0; pexp[1][r] = p1;
        }

        // ---- rescale O, write P (D-layout -> LDS), reload as A-layout ----
        #pragma unroll
        for (int dt = 0; dt < 4; ++dt)
            #pragma unroll
            for (int r = 0; r < 4; ++r)
                acc[dt][r] *= alpha[r];

        unsigned short* P = Plds[wave];
        #pragma unroll
        for (int kt = 0; kt < 2; ++kt)
            #pragma unroll
            for (int r = 0; r < 4; ++r)
                P[(4 * g + r) * 40 + 16 * kt + l15] = f2bf(pexp[kt][r]);

        __asm__ volatile("s_waitcnt lgkmcnt(0)" ::: "memory");   // wave-local P RAW

        short8 pf = *(const short8*)((const char*)P + (l15 * 40 + g * 8) * 2);

        // ---- O += P·V  (B-frag from V^T: row d = dt*16+l15, k chunk g) ----
        #pragma unroll
        for (int dt = 0; dt < 4; ++dt) {
            short8 vf = *(const short8*)((const char*)Vtlds + ((dt * 16 + l15) * 40 + g * 8) * 2);
            acc[dt] = __builtin_amdgcn_mfma_f32_16x16x32_bf16(pf, vf, acc[dt], 0, 0, 0);
        }
    }

    // ---- epilogue: O / l ----
    float* Ob = O + ((size_t)b * S_LEN + qbase) * D_K;
    #pragma unroll
    for (int r = 0; r < 4; ++r) {
        const float inv = 1.0f / lrow[r];
        const int row = 16 * wave + 4 * g + r;
        #pragma unroll
        for (int dt = 0; dt < 4; ++dt)
            Ob[(size_t)row * D_K + dt * 16 + l15] = acc[dt][r] * inv;
    }
}

extern "C" void kernel_launch(void* const* d_in, const int* in_sizes, int n_in,
                              void* d_out, int out_size, void* d_ws, size_t ws_size,
                              hipStream_t stream) {
    const float* Q = (const float*)d_in[0];
    const float* K = (const float*)d_in[1];
    const float* V = (const float*)d_in[2];
    const float* M = (const float*)d_in[3];
    float* O = (float*)d_out;
    dim3 grid(S_LEN / QT, N_B);
    attn_fwd<<<grid, 256, 0, stream>>>(Q, K, V, M, O);
}

// Round 2
// 131.709 us; speedup vs baseline: 1.6611x; 1.6611x over previous
//
#include <hip/hip_runtime.h>
#include <hip/hip_bf16.h>

// Attention: B=4, S=4096, D=64, fp32 in/out, causal + additive padding mask.
// Two-phase: prepass converts K/V/mask into bf16 tiled+swizzled scratch (d_ws),
// main kernel = 1 wave / 16 q-rows, DMA-staged double-buffered flash attention
// with swapped QK^T (in-lane softmax), exp2 folding, defer-max.

#define S_LEN  4096
#define N_B    4
#define NTILE  128                 // S / 32 kv tiles
#define BIGF   1.803368e9f         // (1e10/sqrt(64)) * (1/ln2)
#define QSCALE (0.125f * 1.44269504089f)
#define BIGNEG 1.25e9f             // fallback kernel: INF / sqrt(64)

typedef __attribute__((ext_vector_type(8))) short short8;
typedef __attribute__((ext_vector_type(4))) float f32x4;
typedef __attribute__((ext_vector_type(2))) unsigned int uint2v;
typedef unsigned short ushort_t;

// ws layout (bytes)
#define KT_OFF 0
#define KT_BYTES (N_B * NTILE * 32 * 64 * 2)            // 2,097,152
#define VT_OFF KT_BYTES
#define VT_BYTES (N_B * NTILE * 64 * 40 * 2)            // 2,621,440
#define MA_OFF (KT_OFF + KT_BYTES + VT_BYTES)
#define MA_PAD 4224
#define MA_BYTES (N_B * MA_PAD * 4)                     // 67,584
#define WS_NEEDED (KT_BYTES + VT_BYTES + MA_BYTES)

__device__ __forceinline__ unsigned short f2bf(float f) {
    union { float f; unsigned u; } v; v.f = f;
    unsigned r = v.u + 0x7FFF + ((v.u >> 16) & 1);   // RNE
    return (unsigned short)(r >> 16);
}

__device__ __forceinline__ void ld_lds16(const void* g, void* l) {
    __builtin_amdgcn_global_load_lds((const __attribute__((address_space(1))) void*)g,
                                     (__attribute__((address_space(3))) void*)l, 16, 0, 0);
}
__device__ __forceinline__ void ld_lds4(const void* g, void* l) {
    __builtin_amdgcn_global_load_lds((const __attribute__((address_space(1))) void*)g,
                                     (__attribute__((address_space(3))) void*)l, 4, 0, 0);
}

// ---------------- prepass kernels ----------------

// K -> bf16 tiled [b][t][32 rows][8 chunks of 16B], chunk XOR-swizzled by row&7
__global__ __launch_bounds__(64)
void prep_k(const float* __restrict__ K, ushort_t* __restrict__ Kt) {
    const int wg = blockIdx.x, b = wg >> 7, t = wg & 127, tid = threadIdx.x;
    const float* in = K + ((size_t)(b * S_LEN + t * 32)) * 64;
    ushort_t* out = Kt + (size_t)(b * NTILE + t) * 2048;
    #pragma unroll
    for (int it = 0; it < 4; ++it) {
        const int ch = it * 64 + tid, row = ch >> 3, c = ch & 7;
        const float* src = in + row * 64 + c * 8;
        short8 v;
        #pragma unroll
        for (int j = 0; j < 8; ++j) v[j] = (short)f2bf(src[j]);
        *(short8*)(out + row * 64 + ((c ^ (row & 7)) * 8)) = v;
    }
}

// V -> bf16 transposed padded tiles [b][t][64 d][40 k] (cols 32..39 garbage, never read)
__global__ __launch_bounds__(64)
void prep_v(const float* __restrict__ V, ushort_t* __restrict__ Vt) {
    const int wg = blockIdx.x, b = wg >> 7, t = wg & 127, d = threadIdx.x;
    float vals[32];
    #pragma unroll
    for (int kk = 0; kk < 32; ++kk)
        vals[kk] = V[((size_t)(b * S_LEN + t * 32 + kk)) * 64 + d];
    ushort_t* row = Vt + (size_t)(b * NTILE + t) * 2560 + d * 40;
    #pragma unroll
    for (int c = 0; c < 4; ++c) {
        short8 w;
        #pragma unroll
        for (int j = 0; j < 8; ++j) w[j] = (short)f2bf(vals[c * 8 + j]);
        *(short8*)(row + c * 8) = w;
    }
}

// mask -> additive fp32 term (already exp2-scaled): (1-m)*BIGF, padded to 4224
__global__ __launch_bounds__(256)
void prep_m(const float* __restrict__ M, float* __restrict__ Ma) {
    const int b = blockIdx.x;
    for (int i = threadIdx.x; i < MA_PAD; i += 256)
        Ma[b * MA_PAD + i] = (i < S_LEN) ? (1.0f - M[b * S_LEN + i]) * BIGF : 0.0f;
}

// ---------------- main flash kernel: 1 wave / WG, 16 q-rows ----------------

__global__ __launch_bounds__(64, 2)
void attn_fa(const float* __restrict__ Q, const ushort_t* __restrict__ Kt,
             const ushort_t* __restrict__ Vt, const float* __restrict__ Ma,
             float* __restrict__ O)
{
    const int bid = blockIdx.x;
    const int b   = bid & 3;
    const int tq  = 255 - (bid >> 2);        // longest-work tiles dispatched first
    const int qbase = tq * 16;
    const int lane = threadIdx.x;
    const int l15 = lane & 15;
    const int g   = lane >> 4;

    __shared__ __attribute__((aligned(16))) ushort_t Kb[2][2048];   // [32][64] swizzled
    __shared__ __attribute__((aligned(16))) ushort_t Vb[2][2560];   // [64][40]
    __shared__ __attribute__((aligned(16))) ushort_t Pl[640];       // [16][40]
    __shared__ __attribute__((aligned(16))) float    Ml[2][64];

    // ---- Q as B-fragment (n = l15 = q row, k = g*8+j), scale+ln2 folded ----
    const float* Qrow = Q + ((size_t)(b * S_LEN + qbase + l15)) * 64 + g * 8;
    short8 qf0, qf1;
    #pragma unroll
    for (int j = 0; j < 8; ++j) {
        qf0[j] = (short)f2bf(Qrow[j]      * QSCALE);
        qf1[j] = (short)f2bf(Qrow[32 + j] * QSCALE);
    }
    __asm__ volatile("s_waitcnt vmcnt(0)" ::: "memory");  // drain Q loads before DMA

    const char*  KtB = (const char*)Kt + (size_t)b * NTILE * 4096;
    const char*  VtB = (const char*)Vt + (size_t)b * NTILE * 5120;
    const float* MaB = Ma + b * MA_PAD;

    auto stage = [&](int buf, int t) {
        const char* kg = KtB + (size_t)t * 4096 + lane * 16;
        char* kl = (char*)&Kb[buf][0];
        ld_lds16(kg,        kl);
        ld_lds16(kg + 1024, kl + 1024);
        ld_lds16(kg + 2048, kl + 2048);
        ld_lds16(kg + 3072, kl + 3072);
        const char* vg = VtB + (size_t)t * 5120 + lane * 16;
        char* vl = (char*)&Vb[buf][0];
        ld_lds16(vg,        vl);
        ld_lds16(vg + 1024, vl + 1024);
        ld_lds16(vg + 2048, vl + 2048);
        ld_lds16(vg + 3072, vl + 3072);
        ld_lds16(vg + 4096, vl + 4096);
        ld_lds4(MaB + t * 32 + lane, &Ml[buf][0]);
    };  // exactly 10 vmcnt events

    f32x4 acc[4];
    #pragma unroll
    for (int dt = 0; dt < 4; ++dt) acc[dt] = (f32x4){0.f, 0.f, 0.f, 0.f};
    float mx = -3.0e38f, lsum = 0.f;          // per q = l15 (replicated over g)

    const int nkv = (tq + 2) >> 1;
    stage(0, 0);

    for (int it = 0; it < nkv; ++it) {
        const int buf = it & 1;
        if (it + 1 < nkv) {
            stage(buf ^ 1, it + 1);
            __asm__ volatile("s_waitcnt vmcnt(10)" ::: "memory");
        } else {
            __asm__ volatile("s_waitcnt vmcnt(0)" ::: "memory");
        }
        __builtin_amdgcn_sched_barrier(0);

        // ---- S^T = K · Q^T : rows k = 16kt + 4g + r, cols q = l15 ----
        const ushort_t* kb = Kb[buf];
        f32x4 st0 = (f32x4){0.f,0.f,0.f,0.f}, st1 = st0;
        #pragma unroll
        for (int dc = 0; dc < 2; ++dc) {
            const int r0 = l15;                   // kt = 0
            short8 kf0 = *(const short8*)(kb + r0 * 64 + (((dc * 4 + g) ^ (r0 & 7)) * 8));
            st0 = __builtin_amdgcn_mfma_f32_16x16x32_bf16(kf0, dc ? qf1 : qf0, st0, 0, 0, 0);
            const int r1 = 16 + l15;              // kt = 1
            short8 kf1 = *(const short8*)(kb + r1 * 64 + (((dc * 4 + g) ^ (r1 & 7)) * 8));
            st1 = __builtin_amdgcn_mfma_f32_16x16x32_bf16(kf1, dc ? qf1 : qf0, st1, 0, 0, 0);
        }

        // ---- additive padding mask (broadcast LDS reads) ----
        const f32x4 m0 = *(const f32x4*)&Ml[buf][4 * g];
        const f32x4 m1 = *(const f32x4*)&Ml[buf][16 + 4 * g];
        st0 -= m0;
        st1 -= m1;

        // ---- causal mask: only the last kv tile touches the diagonal ----
        if (it == nkv - 1) {
            const int qg = qbase + l15 - it * 32 - 4 * g;   // keep while 16kt+r <= qg
            #pragma unroll
            for (int r = 0; r < 4; ++r) {
                st0[r] = (r > qg)      ? -BIGF : st0[r];
                st1[r] = (16 + r > qg) ? -BIGF : st1[r];
            }
        }

        // ---- online softmax (per q-col: in-lane over 8 regs + 2 shuffles) ----
        float tm = fmaxf(fmaxf(fmaxf(st0[0], st0[1]), fmaxf(st0[2], st0[3])),
                         fmaxf(fmaxf(st1[0], st1[1]), fmaxf(st1[2], st1[3])));
        tm = fmaxf(tm, __shfl_xor(tm, 16));
        tm = fmaxf(tm, __shfl_xor(tm, 32));

        if (__any(tm > mx + 8.0f)) {             // defer-max (T13)
            const float mnew = fmaxf(mx, tm);
            const float al   = exp2f(mx - mnew);
            const float a0 = __shfl(al, 4 * g + 0);
            const float a1 = __shfl(al, 4 * g + 1);
            const float a2 = __shfl(al, 4 * g + 2);
            const float a3 = __shfl(al, 4 * g + 3);
            #pragma unroll
            for (int dt = 0; dt < 4; ++dt) {
                acc[dt][0] *= a0; acc[dt][1] *= a1;
                acc[dt][2] *= a2; acc[dt][3] *= a3;
            }
            lsum *= al;
            mx = mnew;
        }

        float p0[4], p1[4];
        #pragma unroll
        for (int r = 0; r < 4; ++r) {
            p0[r] = exp2f(st0[r] - mx);
            p1[r] = exp2f(st1[r] - mx);
        }
        float rs = ((p0[0] + p0[1]) + (p0[2] + p0[3]))
                 + ((p1[0] + p1[1]) + (p1[2] + p1[3]));
        rs += __shfl_xor(rs, 16);
        rs += __shfl_xor(rs, 32);
        lsum += rs;

        // ---- P -> bf16 -> LDS (packed b64 writes), then PV ----
        unsigned c00, c01, c10, c11;
        __asm__("v_cvt_pk_bf16_f32 %0, %1, %2" : "=v"(c00) : "v"(p0[0]), "v"(p0[1]));
        __asm__("v_cvt_pk_bf16_f32 %0, %1, %2" : "=v"(c01) : "v"(p0[2]), "v"(p0[3]));
        __asm__("v_cvt_pk_bf16_f32 %0, %1, %2" : "=v"(c10) : "v"(p1[0]), "v"(p1[1]));
        __asm__("v_cvt_pk_bf16_f32 %0, %1, %2" : "=v"(c11) : "v"(p1[2]), "v"(p1[3]));
        *(uint2v*)&Pl[l15 * 40 + 4 * g]      = (uint2v){c00, c01};
        *(uint2v*)&Pl[l15 * 40 + 16 + 4 * g] = (uint2v){c10, c11};

        __asm__ volatile("s_waitcnt lgkmcnt(0)" ::: "memory");
        __builtin_amdgcn_sched_barrier(0);

        short8 pf = *(const short8*)&Pl[l15 * 40 + g * 8];
        const ushort_t* vb = Vb[buf];
        #pragma unroll
        for (int dt = 0; dt < 4; ++dt) {
            short8 vf = *(const short8*)&vb[(16 * dt + l15) * 40 + g * 8];
            acc[dt] = __builtin_amdgcn_mfma_f32_16x16x32_bf16(pf, vf, acc[dt], 0, 0, 0);
        }
    }

    // ---- epilogue: O[q=4g+r][d=16dt+l15] = acc/l ----
    const float il0 = 1.0f / __shfl(lsum, 4 * g + 0);
    const float il1 = 1.0f / __shfl(lsum, 4 * g + 1);
    const float il2 = 1.0f / __shfl(lsum, 4 * g + 2);
    const float il3 = 1.0f / __shfl(lsum, 4 * g + 3);
    float* Ob = O + ((size_t)(b * S_LEN + qbase)) * 64;
    #pragma unroll
    for (int dt = 0; dt < 4; ++dt) {
        Ob[(4 * g + 0) * 64 + 16 * dt + l15] = acc[dt][0] * il0;
        Ob[(4 * g + 1) * 64 + 16 * dt + l15] = acc[dt][1] * il1;
        Ob[(4 * g + 2) * 64 + 16 * dt + l15] = acc[dt][2] * il2;
        Ob[(4 * g + 3) * 64 + 16 * dt + l15] = acc[dt][3] * il3;
    }
}

// ---------------- fallback (round-1 kernel) if ws too small ----------------

__global__ __launch_bounds__(256)
void attn_fwd_fb(const float* __restrict__ Q, const float* __restrict__ K,
                 const float* __restrict__ V, const float* __restrict__ M,
                 float* __restrict__ O)
{
    const int tile  = blockIdx.x;
    const int b     = blockIdx.y;
    const int qbase = tile * 64;
    const int tid   = threadIdx.x;
    const int wave  = tid >> 6;
    const int lane  = tid & 63;
    const int l15   = lane & 15;
    const int g     = lane >> 4;

    __shared__ __attribute__((aligned(16))) unsigned short Klds[32 * 64];
    __shared__ __attribute__((aligned(16))) unsigned short Vtlds[64 * 40];
    __shared__ __attribute__((aligned(16))) unsigned short Plds[4][16 * 40];

    const float* Qb = Q + ((size_t)b * S_LEN + qbase) * 64;
    const float* Kb = K + (size_t)b * S_LEN * 64;
    const float* Vb = V + (size_t)b * S_LEN * 64;
    const float* Mb = M + (size_t)b * S_LEN;

    const int qrow = 16 * wave + l15;
    short8 qf[2];
    #pragma unroll
    for (int dc = 0; dc < 2; ++dc) {
        const float* src = Qb + (size_t)qrow * 64 + dc * 32 + g * 8;
        #pragma unroll
        for (int j = 0; j < 8; ++j) qf[dc][j] = (short)f2bf(src[j] * 0.125f);
    }

    f32x4 acc[4];
    #pragma unroll
    for (int dt = 0; dt < 4; ++dt) acc[dt] = (f32x4){0.f, 0.f, 0.f, 0.f};
    float mrow[4], lrow[4];
    #pragma unroll
    for (int r = 0; r < 4; ++r) { mrow[r] = -1e30f; lrow[r] = 0.f; }

    const int q_max_wave = qbase + 16 * wave + 15;
    const int nkv = (qbase + 64) / 32;

    for (int it = 0; it < nkv; ++it) {
        const int kv = it * 32;
        __syncthreads();
        {
            const int k = tid >> 3, c = tid & 7;
            const float* src = Kb + (size_t)(kv + k) * 64 + c * 8;
            short8 t8;
            #pragma unroll
            for (int j = 0; j < 8; ++j) t8[j] = (short)f2bf(src[j]);
            const int byte = k * 128 + ((c * 16) ^ ((k & 7) << 4));
            *(short8*)((char*)Klds + byte) = t8;
        }
        {
            const int k = tid & 31, dch = tid >> 5;
            const float* src = Vb + (size_t)(kv + k) * 64 + dch * 8;
            #pragma unroll
            for (int j = 0; j < 8; ++j)
                Vtlds[(dch * 8 + j) * 40 + k] = f2bf(src[j]);
        }
        __syncthreads();

        if (kv > q_max_wave) continue;

        f32x4 s[2];
        s[0] = (f32x4){0.f,0.f,0.f,0.f};
        s[1] = (f32x4){0.f,0.f,0.f,0.f};
        #pragma unroll
        for (int kt = 0; kt < 2; ++kt) {
            const int krow = 16 * kt + l15;
            #pragma unroll
            for (int dc = 0; dc < 2; ++dc) {
                const int byte = krow * 128 + ((dc * 64 + g * 16) ^ ((krow & 7) << 4));
                short8 kf = *(const short8*)((const char*)Klds + byte);
                s[kt] = __builtin_amdgcn_mfma_f32_16x16x32_bf16(qf[dc], kf, s[kt], 0, 0, 0);
            }
        }

        float mk0 = Mb[kv + l15];
        float mk1 = Mb[kv + 16 + l15];
        #pragma unroll
        for (int kt = 0; kt < 2; ++kt) {
            const int gk = kv + 16 * kt + l15;
            const float madd = (1.0f - (kt ? mk1 : mk0)) * BIGNEG;
            #pragma unroll
            for (int r = 0; r < 4; ++r) {
                const int gq = qbase + 16 * wave + 4 * g + r;
                float v = s[kt][r] - madd;
                if (gk > gq) v -= BIGNEG;
                s[kt][r] = v;
            }
        }

        float pexp[2][4], alpha[4];
        #pragma unroll
        for (int r = 0; r < 4; ++r) {
            float tm = fmaxf(s[0][r], s[1][r]);
            #pragma unroll
            for (int off = 8; off >= 1; off >>= 1)
                tm = fmaxf(tm, __shfl_xor(tm, off, 64));
            const float mnew = fmaxf(mrow[r], tm);
            const float a  = __expf(mrow[r] - mnew);
            const float p0 = __expf(s[0][r] - mnew);
            const float p1 = __expf(s[1][r] - mnew);
            float rs = p0 + p1;
            #pragma unroll
            for (int off = 8; off >= 1; off >>= 1)
                rs += __shfl_xor(rs, off, 64);
            lrow[r] = lrow[r] * a + rs;
            mrow[r] = mnew;
            alpha[r] = a;
            pexp[0][r] = p0; pexp[1][r] = p1;
        }

        #pragma unroll
        for (int dt = 0; dt < 4; ++dt)
            #pragma unroll
            for (int r = 0; r < 4; ++r)
                acc[dt][r] *= alpha[r];

        unsigned short* P = Plds[wave];
        #pragma unroll
        for (int kt = 0; kt < 2; ++kt)
            #pragma unroll
            for (int r = 0; r < 4; ++r)
                P[(4 * g + r) * 40 + 16 * kt + l15] = f2bf(pexp[kt][r]);

        __asm__ volatile("s_waitcnt lgkmcnt(0)" ::: "memory");

        short8 pf = *(const short8*)((const char*)P + (l15 * 40 + g * 8) * 2);
        #pragma unroll
        for (int dt = 0; dt < 4; ++dt) {
            short8 vf = *(const short8*)((const char*)Vtlds + ((dt * 16 + l15) * 40 + g * 8) * 2);
            acc[dt] = __builtin_amdgcn_mfma_f32_16x16x32_bf16(pf, vf, acc[dt], 0, 0, 0);
        }
    }

    float* Ob = O + ((size_t)b * S_LEN + qbase) * 64;
    #pragma unroll
    for (int r = 0; r < 4; ++r) {
        const float inv = 1.0f / lrow[r];
        const int row = 16 * wave + 4 * g + r;
        #pragma unroll
        for (int dt = 0; dt < 4; ++dt)
            Ob[(size_t)row * 64 + dt * 16 + l15] = acc[dt][r] * inv;
    }
}

extern "C" void kernel_launch(void* const* d_in, const int* in_sizes, int n_in,
                              void* d_out, int out_size, void* d_ws, size_t ws_size,
                              hipStream_t stream) {
    const float* Q = (const float*)d_in[0];
    const float* K = (const float*)d_in[1];
    const float* V = (const float*)d_in[2];
    const float* M = (const float*)d_in[3];
    float* O = (float*)d_out;

    if (ws_size >= (size_t)WS_NEEDED) {
        ushort_t* Kt = (ushort_t*)((char*)d_ws + KT_OFF);
        ushort_t* Vt = (ushort_t*)((char*)d_ws + VT_OFF);
        float*    Ma = (float*)((char*)d_ws + MA_OFF);
        prep_k<<<dim3(N_B * NTILE), 64, 0, stream>>>(K, Kt);
        prep_v<<<dim3(N_B * NTILE), 64, 0, stream>>>(V, Vt);
        prep_m<<<dim3(N_B), 256, 0, stream>>>(M, Ma);
        attn_fa<<<dim3(1024), 64, 0, stream>>>(Q, Kt, Vt, Ma, O);
    } else {
        dim3 grid(S_LEN / 64, N_B);
        attn_fwd_fb<<<grid, 256, 0, stream>>>(Q, K, V, M, O);
    }
}

// Round 3
// 94.496 us; speedup vs baseline: 2.3152x; 1.3938x over previous
//
#include <hip/hip_runtime.h>
#include <hip/hip_bf16.h>

// Attention: B=4, S=4096, D=64, fp32 in/out, causal + additive padding mask.
// Tier-1 (needs ~17 MB ws): prepass -> bf16 K tiles + V^T tiles; split-KV
// flash attention (1 wave / 16 q-rows / <=32 kv-tiles, register-staged,
// 2-deep pipeline); combine kernel merges partials.
// Tier-2 (round-2 path, ~4.8 MB ws) and tier-3 (monolithic) fallbacks kept.

#define S_LEN  4096
#define N_B    4
#define NTILE  128                 // S / 32 kv tiles
#define BIGF   1.803368e9f         // (1e10/sqrt(64)) * (1/ln2)
#define QSCALE (0.125f * 1.44269504089f)
#define BIGNEG 1.25e9f             // tier-3 kernel: INF / sqrt(64)

typedef __attribute__((ext_vector_type(8))) short short8;
typedef __attribute__((ext_vector_type(4))) float f32x4;
typedef __attribute__((ext_vector_type(2))) unsigned int uint2v;
typedef unsigned short ushort_t;

// ---------------- tier-1 ws layout (bytes) ----------------
#define KT2_OFF   0
#define KT2_BYTES (N_B * NTILE * 2048 * 2)        // 2 MB   [b][t][32 k][64 d] bf16
#define VT2_OFF   (KT2_OFF + KT2_BYTES)
#define VT2_BYTES (N_B * NTILE * 2048 * 2)        // 2 MB   [b][t][64 d][32 k] bf16
#define NSLOT     (N_B * 192 * 4)                 // 3072 partial slots (tq>=64)
#define OP_OFF    (VT2_OFF + VT2_BYTES)
#define OP_BYTES  (NSLOT * 16 * 64 * 4)           // 12.58 MB
#define PM_OFF    (OP_OFF + OP_BYTES)
#define PM_BYTES  (NSLOT * 16 * 4)
#define PLS_OFF   (PM_OFF + PM_BYTES)
#define PLS_BYTES (NSLOT * 16 * 4)
#define WS2_NEEDED (PLS_OFF + PLS_BYTES)

// ---------------- tier-2 ws layout ----------------
#define KT_OFF 0
#define KT_BYTES (N_B * NTILE * 32 * 64 * 2)
#define VT_OFF KT_BYTES
#define VT_BYTES (N_B * NTILE * 64 * 40 * 2)
#define MA_OFF (KT_OFF + KT_BYTES + VT_BYTES)
#define MA_PAD 4224
#define MA_BYTES (N_B * MA_PAD * 4)
#define WS_NEEDED (KT_BYTES + VT_BYTES + MA_BYTES)

__device__ __forceinline__ unsigned short f2bf(float f) {
    union { float f; unsigned u; } v; v.f = f;
    unsigned r = v.u + 0x7FFF + ((v.u >> 16) & 1);   // RNE
    return (unsigned short)(r >> 16);
}

__device__ __forceinline__ void ld_lds16(const void* g, void* l) {
    __builtin_amdgcn_global_load_lds((const __attribute__((address_space(1))) void*)g,
                                     (__attribute__((address_space(3))) void*)l, 16, 0, 0);
}
__device__ __forceinline__ void ld_lds4(const void* g, void* l) {
    __builtin_amdgcn_global_load_lds((const __attribute__((address_space(1))) void*)g,
                                     (__attribute__((address_space(3))) void*)l, 4, 0, 0);
}

// =================== tier-1 kernels ===================

// Fused prepass: K -> bf16 [b][t][32][64] (linear); V -> bf16 transposed [b][t][64][32]
__global__ __launch_bounds__(256)
void prep2(const float* __restrict__ K, const float* __restrict__ V,
           ushort_t* __restrict__ Kt, ushort_t* __restrict__ Vt)
{
    const int tile = blockIdx.x, b = blockIdx.y, tid = threadIdx.x;
    // K: thread -> (row = tid>>3, 16B chunk c = tid&7)
    {
        const int row = tid >> 3, c = tid & 7;
        const float* src = K + ((size_t)(b * S_LEN + tile * 32 + row)) * 64 + c * 8;
        const f32x4 a = *(const f32x4*)src;
        const f32x4 d = *(const f32x4*)(src + 4);
        short8 w;
        w[0]=(short)f2bf(a[0]); w[1]=(short)f2bf(a[1]); w[2]=(short)f2bf(a[2]); w[3]=(short)f2bf(a[3]);
        w[4]=(short)f2bf(d[0]); w[5]=(short)f2bf(d[1]); w[6]=(short)f2bf(d[2]); w[7]=(short)f2bf(d[3]);
        *(short8*)(Kt + ((size_t)(b * NTILE + tile)) * 2048 + row * 64 + c * 8) = w;
    }
    // V^T: thread -> (d = tid&63, k-group kg = tid>>6); reads coalesced across d
    {
        const int d = tid & 63, kg = tid >> 6;
        short8 w;
        #pragma unroll
        for (int j = 0; j < 8; ++j)
            w[j] = (short)f2bf(V[((size_t)(b * S_LEN + tile * 32 + kg * 8 + j)) * 64 + d]);
        *(short8*)(Vt + ((size_t)(b * NTILE + tile)) * 2048 + d * 32 + kg * 8) = w;
    }
}

// Split-KV flash kernel: 1 wave, 16 q-rows, kv tiles [32c, min(32c+32, nkv))
__global__ __launch_bounds__(64, 3)
void attn_fa2(const float* __restrict__ Q, const float* __restrict__ M,
              const ushort_t* __restrict__ Kt, const ushort_t* __restrict__ Vt,
              float* __restrict__ Op, float* __restrict__ Pm, float* __restrict__ Pll,
              float* __restrict__ O)
{
    const int x = blockIdx.x, b = blockIdx.y;
    int tq, c;
    if (x < 256)      { tq = 255 - (x >> 2); c = x & 3; }
    else if (x < 448) { const int y = x - 256; const int q3 = y / 3; tq = 191 - q3; c = y - 3 * q3; }
    else if (x < 576) { const int y = x - 448; tq = 127 - (y >> 1); c = y & 1; }
    else              { tq = 63 - (x - 576); c = 0; }

    const int nkv = (tq + 2) >> 1;
    const int t0  = 32 * c;
    const int t1  = (32 * (c + 1) < nkv) ? 32 * (c + 1) : nkv;
    const int qbase = tq * 16;

    const int lane = threadIdx.x, l15 = lane & 15, g = lane >> 4;

    __shared__ __attribute__((aligned(16))) ushort_t Pl[16 * 40];

    // Q as B-fragment (n = l15 = q row, k = g*8+j), scale+1/ln2 folded
    const float* Qrow = Q + ((size_t)(b * S_LEN + qbase + l15)) * 64 + g * 8;
    short8 qf0, qf1;
    #pragma unroll
    for (int j = 0; j < 8; ++j) {
        qf0[j] = (short)f2bf(Qrow[j]      * QSCALE);
        qf1[j] = (short)f2bf(Qrow[32 + j] * QSCALE);
    }

    const char*  ktile = (const char*)Kt + (size_t)b * (NTILE * 4096) + l15 * 128 + g * 16;
    const char*  vtile = (const char*)Vt + (size_t)b * (NTILE * 4096) + l15 * 64  + g * 16;
    const float* Mb    = M + (size_t)b * S_LEN + 4 * g;

    f32x4 acc[4];
    #pragma unroll
    for (int dt = 0; dt < 4; ++dt) acc[dt] = (f32x4){0.f, 0.f, 0.f, 0.f};
    float mx = -3.0e38f, lsum = 0.f;

    short8 kA0,kA1,kA2,kA3, vA0,vA1,vA2,vA3, kB0,kB1,kB2,kB3, vB0,vB1,vB2,vB3;
    f32x4 mA0, mA1, mB0, mB1;

#define LOADSET(SS, tt) do { \
    const char* kp_ = ktile + (size_t)(tt) * 4096; \
    k##SS##0 = *(const short8*)(kp_); \
    k##SS##1 = *(const short8*)(kp_ + 64); \
    k##SS##2 = *(const short8*)(kp_ + 2048); \
    k##SS##3 = *(const short8*)(kp_ + 2048 + 64); \
    const char* vp_ = vtile + (size_t)(tt) * 4096; \
    v##SS##0 = *(const short8*)(vp_); \
    v##SS##1 = *(const short8*)(vp_ + 1024); \
    v##SS##2 = *(const short8*)(vp_ + 2048); \
    v##SS##3 = *(const short8*)(vp_ + 3072); \
    m##SS##0 = *(const f32x4*)(Mb + (tt) * 32); \
    m##SS##1 = *(const f32x4*)(Mb + (tt) * 32 + 16); \
} while (0)

#define COMPUTE(SS, tt) do { \
    const f32x4 z_ = (f32x4){0.f, 0.f, 0.f, 0.f}; \
    f32x4 st0 = __builtin_amdgcn_mfma_f32_16x16x32_bf16(k##SS##0, qf0, z_, 0, 0, 0); \
    st0 = __builtin_amdgcn_mfma_f32_16x16x32_bf16(k##SS##1, qf1, st0, 0, 0, 0); \
    f32x4 st1 = __builtin_amdgcn_mfma_f32_16x16x32_bf16(k##SS##2, qf0, z_, 0, 0, 0); \
    st1 = __builtin_amdgcn_mfma_f32_16x16x32_bf16(k##SS##3, qf1, st1, 0, 0, 0); \
    _Pragma("unroll") \
    for (int r = 0; r < 4; ++r) { \
        st0[r] -= (1.0f - m##SS##0[r]) * BIGF; \
        st1[r] -= (1.0f - m##SS##1[r]) * BIGF; \
    } \
    if ((tt) == nkv - 1) { \
        const int qg = qbase + l15 - (tt) * 32 - 4 * g; \
        _Pragma("unroll") \
        for (int r = 0; r < 4; ++r) { \
            if (r > qg)      st0[r] -= BIGF; \
            if (16 + r > qg) st1[r] -= BIGF; \
        } \
    } \
    float tm = fmaxf(fmaxf(fmaxf(st0[0], st0[1]), fmaxf(st0[2], st0[3])), \
                     fmaxf(fmaxf(st1[0], st1[1]), fmaxf(st1[2], st1[3]))); \
    tm = fmaxf(tm, __shfl_xor(tm, 16)); \
    tm = fmaxf(tm, __shfl_xor(tm, 32)); \
    if (__any(tm > mx + 8.0f)) { \
        const float mnew = fmaxf(mx, tm); \
        const float al   = exp2f(mx - mnew); \
        const float a0 = __shfl(al, 4 * g + 0); \
        const float a1 = __shfl(al, 4 * g + 1); \
        const float a2 = __shfl(al, 4 * g + 2); \
        const float a3 = __shfl(al, 4 * g + 3); \
        _Pragma("unroll") \
        for (int dt = 0; dt < 4; ++dt) { \
            acc[dt][0] *= a0; acc[dt][1] *= a1; \
            acc[dt][2] *= a2; acc[dt][3] *= a3; \
        } \
        lsum *= al; \
        mx = mnew; \
    } \
    float p0[4], p1[4]; \
    _Pragma("unroll") \
    for (int r = 0; r < 4; ++r) { \
        p0[r] = exp2f(st0[r] - mx); \
        p1[r] = exp2f(st1[r] - mx); \
    } \
    float rs = ((p0[0] + p0[1]) + (p0[2] + p0[3])) \
             + ((p1[0] + p1[1]) + (p1[2] + p1[3])); \
    rs += __shfl_xor(rs, 16); \
    rs += __shfl_xor(rs, 32); \
    lsum += rs; \
    unsigned c00, c01, c10, c11; \
    __asm__("v_cvt_pk_bf16_f32 %0, %1, %2" : "=v"(c00) : "v"(p0[0]), "v"(p0[1])); \
    __asm__("v_cvt_pk_bf16_f32 %0, %1, %2" : "=v"(c01) : "v"(p0[2]), "v"(p0[3])); \
    __asm__("v_cvt_pk_bf16_f32 %0, %1, %2" : "=v"(c10) : "v"(p1[0]), "v"(p1[1])); \
    __asm__("v_cvt_pk_bf16_f32 %0, %1, %2" : "=v"(c11) : "v"(p1[2]), "v"(p1[3])); \
    *(uint2v*)&Pl[l15 * 40 + 4 * g]      = (uint2v){c00, c01}; \
    *(uint2v*)&Pl[l15 * 40 + 16 + 4 * g] = (uint2v){c10, c11}; \
    __asm__ volatile("s_waitcnt lgkmcnt(0)" ::: "memory"); \
    __builtin_amdgcn_sched_barrier(0); \
    short8 pf = *(const short8*)&Pl[l15 * 40 + g * 8]; \
    acc[0] = __builtin_amdgcn_mfma_f32_16x16x32_bf16(pf, v##SS##0, acc[0], 0, 0, 0); \
    acc[1] = __builtin_amdgcn_mfma_f32_16x16x32_bf16(pf, v##SS##1, acc[1], 0, 0, 0); \
    acc[2] = __builtin_amdgcn_mfma_f32_16x16x32_bf16(pf, v##SS##2, acc[2], 0, 0, 0); \
    acc[3] = __builtin_amdgcn_mfma_f32_16x16x32_bf16(pf, v##SS##3, acc[3], 0, 0, 0); \
} while (0)

    int t = t0;
    LOADSET(A, t);
    for (;;) {
        if (t + 1 < t1) {
            LOADSET(B, t + 1);
            COMPUTE(A, t);
            ++t;
        } else { COMPUTE(A, t); break; }
        if (t + 1 < t1) {
            LOADSET(A, t + 1);
            COMPUTE(B, t);
            ++t;
        } else { COMPUTE(B, t); break; }
    }
#undef LOADSET
#undef COMPUTE

    if (tq < 64) {
        // single chunk: write final O
        const float il0 = 1.0f / __shfl(lsum, 4 * g + 0);
        const float il1 = 1.0f / __shfl(lsum, 4 * g + 1);
        const float il2 = 1.0f / __shfl(lsum, 4 * g + 2);
        const float il3 = 1.0f / __shfl(lsum, 4 * g + 3);
        float* Ob = O + ((size_t)(b * S_LEN + qbase)) * 64;
        #pragma unroll
        for (int dt = 0; dt < 4; ++dt) {
            Ob[(4 * g + 0) * 64 + 16 * dt + l15] = acc[dt][0] * il0;
            Ob[(4 * g + 1) * 64 + 16 * dt + l15] = acc[dt][1] * il1;
            Ob[(4 * g + 2) * 64 + 16 * dt + l15] = acc[dt][2] * il2;
            Ob[(4 * g + 3) * 64 + 16 * dt + l15] = acc[dt][3] * il3;
        }
    } else {
        // partial: unnormalized O + (m, l) per row
        const int slot = (b * 192 + (tq - 64)) * 4 + c;
        float* Os = Op + (size_t)slot * 1024;
        #pragma unroll
        for (int dt = 0; dt < 4; ++dt) {
            Os[(4 * g + 0) * 64 + 16 * dt + l15] = acc[dt][0];
            Os[(4 * g + 1) * 64 + 16 * dt + l15] = acc[dt][1];
            Os[(4 * g + 2) * 64 + 16 * dt + l15] = acc[dt][2];
            Os[(4 * g + 3) * 64 + 16 * dt + l15] = acc[dt][3];
        }
        if (g == 0) {
            Pm[slot * 16 + l15]  = mx;
            Pll[slot * 16 + l15] = lsum;
        }
    }
}

// Merge partials for tq in [64, 256)
__global__ __launch_bounds__(64)
void combine2(const float* __restrict__ Op, const float* __restrict__ Pm,
              const float* __restrict__ Pll, float* __restrict__ O)
{
    const int tq = 64 + blockIdx.x, b = blockIdx.y, lane = threadIdx.x;
    const int nch = 2 + (tq >= 128) + (tq >= 192);
    const int sbase = (b * 192 + (tq - 64)) * 4;
    for (int r = 0; r < 16; ++r) {
        const float m0 = Pm[(sbase + 0) * 16 + r];
        const float m1 = Pm[(sbase + 1) * 16 + r];
        const float m2 = (nch > 2) ? Pm[(sbase + 2) * 16 + r] : -3.0e38f;
        const float m3 = (nch > 3) ? Pm[(sbase + 3) * 16 + r] : -3.0e38f;
        const float ms = fmaxf(fmaxf(m0, m1), fmaxf(m2, m3));
        const float w0 = exp2f(m0 - ms), w1 = exp2f(m1 - ms);
        const float w2 = (nch > 2) ? exp2f(m2 - ms) : 0.f;
        const float w3 = (nch > 3) ? exp2f(m3 - ms) : 0.f;
        float l = w0 * Pll[(sbase + 0) * 16 + r] + w1 * Pll[(sbase + 1) * 16 + r];
        if (nch > 2) l += w2 * Pll[(sbase + 2) * 16 + r];
        if (nch > 3) l += w3 * Pll[(sbase + 3) * 16 + r];
        float a = w0 * Op[(size_t)(sbase + 0) * 1024 + r * 64 + lane]
                + w1 * Op[(size_t)(sbase + 1) * 1024 + r * 64 + lane];
        if (nch > 2) a += w2 * Op[(size_t)(sbase + 2) * 1024 + r * 64 + lane];
        if (nch > 3) a += w3 * Op[(size_t)(sbase + 3) * 1024 + r * 64 + lane];
        O[((size_t)(b * S_LEN + tq * 16 + r)) * 64 + lane] = a / l;
    }
}

// =================== tier-2 kernels (round-2 path, unchanged) ===================

__global__ __launch_bounds__(64)
void prep_k(const float* __restrict__ K, ushort_t* __restrict__ Kt) {
    const int wg = blockIdx.x, b = wg >> 7, t = wg & 127, tid = threadIdx.x;
    const float* in = K + ((size_t)(b * S_LEN + t * 32)) * 64;
    ushort_t* out = Kt + (size_t)(b * NTILE + t) * 2048;
    #pragma unroll
    for (int it = 0; it < 4; ++it) {
        const int ch = it * 64 + tid, row = ch >> 3, c = ch & 7;
        const float* src = in + row * 64 + c * 8;
        short8 v;
        #pragma unroll
        for (int j = 0; j < 8; ++j) v[j] = (short)f2bf(src[j]);
        *(short8*)(out + row * 64 + ((c ^ (row & 7)) * 8)) = v;
    }
}

__global__ __launch_bounds__(64)
void prep_v(const float* __restrict__ V, ushort_t* __restrict__ Vt) {
    const int wg = blockIdx.x, b = wg >> 7, t = wg & 127, d = threadIdx.x;
    float vals[32];
    #pragma unroll
    for (int kk = 0; kk < 32; ++kk)
        vals[kk] = V[((size_t)(b * S_LEN + t * 32 + kk)) * 64 + d];
    ushort_t* row = Vt + (size_t)(b * NTILE + t) * 2560 + d * 40;
    #pragma unroll
    for (int c = 0; c < 4; ++c) {
        short8 w;
        #pragma unroll
        for (int j = 0; j < 8; ++j) w[j] = (short)f2bf(vals[c * 8 + j]);
        *(short8*)(row + c * 8) = w;
    }
}

__global__ __launch_bounds__(256)
void prep_m(const float* __restrict__ M, float* __restrict__ Ma) {
    const int b = blockIdx.x;
    for (int i = threadIdx.x; i < MA_PAD; i += 256)
        Ma[b * MA_PAD + i] = (i < S_LEN) ? (1.0f - M[b * S_LEN + i]) * BIGF : 0.0f;
}

__global__ __launch_bounds__(64, 2)
void attn_fa(const float* __restrict__ Q, const ushort_t* __restrict__ Kt,
             const ushort_t* __restrict__ Vt, const float* __restrict__ Ma,
             float* __restrict__ O)
{
    const int bid = blockIdx.x;
    const int b   = bid & 3;
    const int tq  = 255 - (bid >> 2);
    const int qbase = tq * 16;
    const int lane = threadIdx.x;
    const int l15 = lane & 15;
    const int g   = lane >> 4;

    __shared__ __attribute__((aligned(16))) ushort_t Kb[2][2048];
    __shared__ __attribute__((aligned(16))) ushort_t Vb[2][2560];
    __shared__ __attribute__((aligned(16))) ushort_t Pl[640];
    __shared__ __attribute__((aligned(16))) float    Ml[2][64];

    const float* Qrow = Q + ((size_t)(b * S_LEN + qbase + l15)) * 64 + g * 8;
    short8 qf0, qf1;
    #pragma unroll
    for (int j = 0; j < 8; ++j) {
        qf0[j] = (short)f2bf(Qrow[j]      * QSCALE);
        qf1[j] = (short)f2bf(Qrow[32 + j] * QSCALE);
    }
    __asm__ volatile("s_waitcnt vmcnt(0)" ::: "memory");

    const char*  KtB = (const char*)Kt + (size_t)b * NTILE * 4096;
    const char*  VtB = (const char*)Vt + (size_t)b * NTILE * 5120;
    const float* MaB = Ma + b * MA_PAD;

    auto stage = [&](int buf, int t) {
        const char* kg = KtB + (size_t)t * 4096 + lane * 16;
        char* kl = (char*)&Kb[buf][0];
        ld_lds16(kg,        kl);
        ld_lds16(kg + 1024, kl + 1024);
        ld_lds16(kg + 2048, kl + 2048);
        ld_lds16(kg + 3072, kl + 3072);
        const char* vg = VtB + (size_t)t * 5120 + lane * 16;
        char* vl = (char*)&Vb[buf][0];
        ld_lds16(vg,        vl);
        ld_lds16(vg + 1024, vl + 1024);
        ld_lds16(vg + 2048, vl + 2048);
        ld_lds16(vg + 3072, vl + 3072);
        ld_lds16(vg + 4096, vl + 4096);
        ld_lds4(MaB + t * 32 + lane, &Ml[buf][0]);
    };

    f32x4 acc[4];
    #pragma unroll
    for (int dt = 0; dt < 4; ++dt) acc[dt] = (f32x4){0.f, 0.f, 0.f, 0.f};
    float mx = -3.0e38f, lsum = 0.f;

    const int nkv = (tq + 2) >> 1;
    stage(0, 0);

    for (int it = 0; it < nkv; ++it) {
        const int buf = it & 1;
        if (it + 1 < nkv) {
            stage(buf ^ 1, it + 1);
            __asm__ volatile("s_waitcnt vmcnt(10)" ::: "memory");
        } else {
            __asm__ volatile("s_waitcnt vmcnt(0)" ::: "memory");
        }
        __builtin_amdgcn_sched_barrier(0);

        const ushort_t* kb = Kb[buf];
        f32x4 st0 = (f32x4){0.f,0.f,0.f,0.f}, st1 = st0;
        #pragma unroll
        for (int dc = 0; dc < 2; ++dc) {
            const int r0 = l15;
            short8 kf0 = *(const short8*)(kb + r0 * 64 + (((dc * 4 + g) ^ (r0 & 7)) * 8));
            st0 = __builtin_amdgcn_mfma_f32_16x16x32_bf16(kf0, dc ? qf1 : qf0, st0, 0, 0, 0);
            const int r1 = 16 + l15;
            short8 kf1 = *(const short8*)(kb + r1 * 64 + (((dc * 4 + g) ^ (r1 & 7)) * 8));
            st1 = __builtin_amdgcn_mfma_f32_16x16x32_bf16(kf1, dc ? qf1 : qf0, st1, 0, 0, 0);
        }

        const f32x4 m0 = *(const f32x4*)&Ml[buf][4 * g];
        const f32x4 m1 = *(const f32x4*)&Ml[buf][16 + 4 * g];
        st0 -= m0;
        st1 -= m1;

        if (it == nkv - 1) {
            const int qg = qbase + l15 - it * 32 - 4 * g;
            #pragma unroll
            for (int r = 0; r < 4; ++r) {
                st0[r] = (r > qg)      ? -BIGF : st0[r];
                st1[r] = (16 + r > qg) ? -BIGF : st1[r];
            }
        }

        float tm = fmaxf(fmaxf(fmaxf(st0[0], st0[1]), fmaxf(st0[2], st0[3])),
                         fmaxf(fmaxf(st1[0], st1[1]), fmaxf(st1[2], st1[3])));
        tm = fmaxf(tm, __shfl_xor(tm, 16));
        tm = fmaxf(tm, __shfl_xor(tm, 32));

        if (__any(tm > mx + 8.0f)) {
            const float mnew = fmaxf(mx, tm);
            const float al   = exp2f(mx - mnew);
            const float a0 = __shfl(al, 4 * g + 0);
            const float a1 = __shfl(al, 4 * g + 1);
            const float a2 = __shfl(al, 4 * g + 2);
            const float a3 = __shfl(al, 4 * g + 3);
            #pragma unroll
            for (int dt = 0; dt < 4; ++dt) {
                acc[dt][0] *= a0; acc[dt][1] *= a1;
                acc[dt][2] *= a2; acc[dt][3] *= a3;
            }
            lsum *= al;
            mx = mnew;
        }

        float p0[4], p1[4];
        #pragma unroll
        for (int r = 0; r < 4; ++r) {
            p0[r] = exp2f(st0[r] - mx);
            p1[r] = exp2f(st1[r] - mx);
        }
        float rs = ((p0[0] + p0[1]) + (p0[2] + p0[3]))
                 + ((p1[0] + p1[1]) + (p1[2] + p1[3]));
        rs += __shfl_xor(rs, 16);
        rs += __shfl_xor(rs, 32);
        lsum += rs;

        unsigned c00, c01, c10, c11;
        __asm__("v_cvt_pk_bf16_f32 %0, %1, %2" : "=v"(c00) : "v"(p0[0]), "v"(p0[1]));
        __asm__("v_cvt_pk_bf16_f32 %0, %1, %2" : "=v"(c01) : "v"(p0[2]), "v"(p0[3]));
        __asm__("v_cvt_pk_bf16_f32 %0, %1, %2" : "=v"(c10) : "v"(p1[0]), "v"(p1[1]));
        __asm__("v_cvt_pk_bf16_f32 %0, %1, %2" : "=v"(c11) : "v"(p1[2]), "v"(p1[3]));
        *(uint2v*)&Pl[l15 * 40 + 4 * g]      = (uint2v){c00, c01};
        *(uint2v*)&Pl[l15 * 40 + 16 + 4 * g] = (uint2v){c10, c11};

        __asm__ volatile("s_waitcnt lgkmcnt(0)" ::: "memory");
        __builtin_amdgcn_sched_barrier(0);

        short8 pf = *(const short8*)&Pl[l15 * 40 + g * 8];
        const ushort_t* vb = Vb[buf];
        #pragma unroll
        for (int dt = 0; dt < 4; ++dt) {
            short8 vf = *(const short8*)&vb[(16 * dt + l15) * 40 + g * 8];
            acc[dt] = __builtin_amdgcn_mfma_f32_16x16x32_bf16(pf, vf, acc[dt], 0, 0, 0);
        }
    }

    const float il0 = 1.0f / __shfl(lsum, 4 * g + 0);
    const float il1 = 1.0f / __shfl(lsum, 4 * g + 1);
    const float il2 = 1.0f / __shfl(lsum, 4 * g + 2);
    const float il3 = 1.0f / __shfl(lsum, 4 * g + 3);
    float* Ob = O + ((size_t)(b * S_LEN + qbase)) * 64;
    #pragma unroll
    for (int dt = 0; dt < 4; ++dt) {
        Ob[(4 * g + 0) * 64 + 16 * dt + l15] = acc[dt][0] * il0;
        Ob[(4 * g + 1) * 64 + 16 * dt + l15] = acc[dt][1] * il1;
        Ob[(4 * g + 2) * 64 + 16 * dt + l15] = acc[dt][2] * il2;
        Ob[(4 * g + 3) * 64 + 16 * dt + l15] = acc[dt][3] * il3;
    }
}

// =================== tier-3 fallback (no ws) ===================

__global__ __launch_bounds__(256)
void attn_fwd_fb(const float* __restrict__ Q, const float* __restrict__ K,
                 const float* __restrict__ V, const float* __restrict__ M,
                 float* __restrict__ O)
{
    const int tile  = blockIdx.x;
    const int b     = blockIdx.y;
    const int qbase = tile * 64;
    const int tid   = threadIdx.x;
    const int wave  = tid >> 6;
    const int lane  = tid & 63;
    const int l15   = lane & 15;
    const int g     = lane >> 4;

    __shared__ __attribute__((aligned(16))) unsigned short Klds[32 * 64];
    __shared__ __attribute__((aligned(16))) unsigned short Vtlds[64 * 40];
    __shared__ __attribute__((aligned(16))) unsigned short Plds[4][16 * 40];

    const float* Qb = Q + ((size_t)b * S_LEN + qbase) * 64;
    const float* Kb = K + (size_t)b * S_LEN * 64;
    const float* Vb = V + (size_t)b * S_LEN * 64;
    const float* Mb = M + (size_t)b * S_LEN;

    const int qrow = 16 * wave + l15;
    short8 qf[2];
    #pragma unroll
    for (int dc = 0; dc < 2; ++dc) {
        const float* src = Qb + (size_t)qrow * 64 + dc * 32 + g * 8;
        #pragma unroll
        for (int j = 0; j < 8; ++j) qf[dc][j] = (short)f2bf(src[j] * 0.125f);
    }

    f32x4 acc[4];
    #pragma unroll
    for (int dt = 0; dt < 4; ++dt) acc[dt] = (f32x4){0.f, 0.f, 0.f, 0.f};
    float mrow[4], lrow[4];
    #pragma unroll
    for (int r = 0; r < 4; ++r) { mrow[r] = -1e30f; lrow[r] = 0.f; }

    const int q_max_wave = qbase + 16 * wave + 15;
    const int nkv = (qbase + 64) / 32;

    for (int it = 0; it < nkv; ++it) {
        const int kv = it * 32;
        __syncthreads();
        {
            const int k = tid >> 3, c = tid & 7;
            const float* src = Kb + (size_t)(kv + k) * 64 + c * 8;
            short8 t8;
            #pragma unroll
            for (int j = 0; j < 8; ++j) t8[j] = (short)f2bf(src[j]);
            const int byte = k * 128 + ((c * 16) ^ ((k & 7) << 4));
            *(short8*)((char*)Klds + byte) = t8;
        }
        {
            const int k = tid & 31, dch = tid >> 5;
            const float* src = Vb + (size_t)(kv + k) * 64 + dch * 8;
            #pragma unroll
            for (int j = 0; j < 8; ++j)
                Vtlds[(dch * 8 + j) * 40 + k] = f2bf(src[j]);
        }
        __syncthreads();

        if (kv > q_max_wave) continue;

        f32x4 s[2];
        s[0] = (f32x4){0.f,0.f,0.f,0.f};
        s[1] = (f32x4){0.f,0.f,0.f,0.f};
        #pragma unroll
        for (int kt = 0; kt < 2; ++kt) {
            const int krow = 16 * kt + l15;
            #pragma unroll
            for (int dc = 0; dc < 2; ++dc) {
                const int byte = krow * 128 + ((dc * 64 + g * 16) ^ ((krow & 7) << 4));
                short8 kf = *(const short8*)((const char*)Klds + byte);
                s[kt] = __builtin_amdgcn_mfma_f32_16x16x32_bf16(qf[dc], kf, s[kt], 0, 0, 0);
            }
        }

        float mk0 = Mb[kv + l15];
        float mk1 = Mb[kv + 16 + l15];
        #pragma unroll
        for (int kt = 0; kt < 2; ++kt) {
            const int gk = kv + 16 * kt + l15;
            const float madd = (1.0f - (kt ? mk1 : mk0)) * BIGNEG;
            #pragma unroll
            for (int r = 0; r < 4; ++r) {
                const int gq = qbase + 16 * wave + 4 * g + r;
                float v = s[kt][r] - madd;
                if (gk > gq) v -= BIGNEG;
                s[kt][r] = v;
            }
        }

        float pexp[2][4], alpha[4];
        #pragma unroll
        for (int r = 0; r < 4; ++r) {
            float tm = fmaxf(s[0][r], s[1][r]);
            #pragma unroll
            for (int off = 8; off >= 1; off >>= 1)
                tm = fmaxf(tm, __shfl_xor(tm, off, 64));
            const float mnew = fmaxf(mrow[r], tm);
            const float a  = __expf(mrow[r] - mnew);
            const float p0 = __expf(s[0][r] - mnew);
            const float p1 = __expf(s[1][r] - mnew);
            float rs = p0 + p1;
            #pragma unroll
            for (int off = 8; off >= 1; off >>= 1)
                rs += __shfl_xor(rs, off, 64);
            lrow[r] = lrow[r] * a + rs;
            mrow[r] = mnew;
            alpha[r] = a;
            pexp[0][r] = p0; pexp[1][r] = p1;
        }

        #pragma unroll
        for (int dt = 0; dt < 4; ++dt)
            #pragma unroll
            for (int r = 0; r < 4; ++r)
                acc[dt][r] *= alpha[r];

        unsigned short* P = Plds[wave];
        #pragma unroll
        for (int kt = 0; kt < 2; ++kt)
            #pragma unroll
            for (int r = 0; r < 4; ++r)
                P[(4 * g + r) * 40 + 16 * kt + l15] = f2bf(pexp[kt][r]);

        __asm__ volatile("s_waitcnt lgkmcnt(0)" ::: "memory");

        short8 pf = *(const short8*)((const char*)P + (l15 * 40 + g * 8) * 2);
        #pragma unroll
        for (int dt = 0; dt < 4; ++dt) {
            short8 vf = *(const short8*)((const char*)Vtlds + ((dt * 16 + l15) * 40 + g * 8) * 2);
            acc[dt] = __builtin_amdgcn_mfma_f32_16x16x32_bf16(pf, vf, acc[dt], 0, 0, 0);
        }
    }

    float* Ob = O + ((size_t)b * S_LEN + qbase) * 64;
    #pragma unroll
    for (int r = 0; r < 4; ++r) {
        const float inv = 1.0f / lrow[r];
        const int row = 16 * wave + 4 * g + r;
        #pragma unroll
        for (int dt = 0; dt < 4; ++dt)
            Ob[(size_t)row * 64 + dt * 16 + l15] = acc[dt][r] * inv;
    }
}

extern "C" void kernel_launch(void* const* d_in, const int* in_sizes, int n_in,
                              void* d_out, int out_size, void* d_ws, size_t ws_size,
                              hipStream_t stream) {
    const float* Q = (const float*)d_in[0];
    const float* K = (const float*)d_in[1];
    const float* V = (const float*)d_in[2];
    const float* M = (const float*)d_in[3];
    float* O = (float*)d_out;

    if (ws_size >= (size_t)WS2_NEEDED) {
        ushort_t* Kt = (ushort_t*)((char*)d_ws + KT2_OFF);
        ushort_t* Vt = (ushort_t*)((char*)d_ws + VT2_OFF);
        float*    Op = (float*)((char*)d_ws + OP_OFF);
        float*    Pm = (float*)((char*)d_ws + PM_OFF);
        float*    Pll= (float*)((char*)d_ws + PLS_OFF);
        prep2<<<dim3(NTILE, N_B), 256, 0, stream>>>(K, V, Kt, Vt);
        attn_fa2<<<dim3(640, N_B), 64, 0, stream>>>(Q, M, Kt, Vt, Op, Pm, Pll, O);
        combine2<<<dim3(192, N_B), 64, 0, stream>>>(Op, Pm, Pll, O);
    } else if (ws_size >= (size_t)WS_NEEDED) {
        ushort_t* Kt = (ushort_t*)((char*)d_ws + KT_OFF);
        ushort_t* Vt = (ushort_t*)((char*)d_ws + VT_OFF);
        float*    Ma = (float*)((char*)d_ws + MA_OFF);
        prep_k<<<dim3(N_B * NTILE), 64, 0, stream>>>(K, Kt);
        prep_v<<<dim3(N_B * NTILE), 64, 0, stream>>>(V, Vt);
        prep_m<<<dim3(N_B), 256, 0, stream>>>(M, Ma);
        attn_fa<<<dim3(1024), 64, 0, stream>>>(Q, Kt, Vt, Ma, O);
    } else {
        dim3 grid(S_LEN / 64, N_B);
        attn_fwd_fb<<<grid, 256, 0, stream>>>(Q, K, V, M, O);
    }
}

// Round 4
// 79.416 us; speedup vs baseline: 2.7549x; 1.1899x over previous
//
#include <hip/hip_runtime.h>
#include <hip/hip_bf16.h>

// Attention: B=4, S=4096, D=64, fp32 in/out, causal + additive padding mask.
// Tier-1 (~13.9 MB ws): prepass -> bf16 K tiles + V^T tiles; fine-grained
// split-KV flash attention (1 wave / 16 q-rows / <=16 kv-tiles of 32,
// register-staged 2-deep pipeline, in-lane softmax); bf16 partials; combine.
// Tier-3 fallback (monolithic, no ws) kept for safety.

#define S_LEN  4096
#define N_B    4
#define NTILE  128                 // S / 32 kv tiles
#define BIGF   1.803368e9f         // (1e10/sqrt(64)) * (1/ln2)
#define QSCALE (0.125f * 1.44269504089f)
#define BIGNEG 1.25e9f             // tier-3: INF / sqrt(64)

typedef __attribute__((ext_vector_type(8))) short short8;
typedef __attribute__((ext_vector_type(4))) float f32x4;
typedef __attribute__((ext_vector_type(2))) unsigned int uint2v;
typedef unsigned short ushort_t;

// ---------------- tier-1 ws layout (bytes) ----------------
// jobs per batch: sum_{tq=0..255} ceil((tq+1)/32) = 1152; singles = 32 (tq<32)
// partial slots per batch = 1120; total 4480.
#define KT2_OFF   0
#define KT2_BYTES (N_B * NTILE * 2048 * 2)        // 2 MB  [b][t][32 k][64 d] bf16
#define VT2_OFF   (KT2_OFF + KT2_BYTES)
#define VT2_BYTES (N_B * NTILE * 2048 * 2)        // 2 MB  [b][t][64 d][32 k] bf16
#define NSLOT     (N_B * 1120)
#define OP_OFF    (VT2_OFF + VT2_BYTES)
#define OP_BYTES  (NSLOT * 512 * 4)               // bf16 pairs: [slot][64 d][8 qpair u32]
#define PM_OFF    (OP_OFF + OP_BYTES)
#define PM_BYTES  (NSLOT * 16 * 4)
#define PLS_OFF   (PM_OFF + PM_BYTES)
#define PLS_BYTES (NSLOT * 16 * 4)
#define WS3_NEEDED (PLS_OFF + PLS_BYTES)          // ~13.9 MB

__device__ __forceinline__ unsigned short f2bf(float f) {
    union { float f; unsigned u; } v; v.f = f;
    unsigned r = v.u + 0x7FFF + ((v.u >> 16) & 1);   // RNE
    return (unsigned short)(r >> 16);
}
__device__ __forceinline__ float bflo(unsigned u) {
    union { unsigned u; float f; } v; v.u = u << 16; return v.f;
}
__device__ __forceinline__ float bfhi(unsigned u) {
    union { unsigned u; float f; } v; v.u = u & 0xffff0000u; return v.f;
}

// =================== tier-1 kernels ===================

// Fused prepass: K -> bf16 [b][t][32][64]; V -> bf16 transposed [b][t][64][32]
__global__ __launch_bounds__(256)
void prep2(const float* __restrict__ K, const float* __restrict__ V,
           ushort_t* __restrict__ Kt, ushort_t* __restrict__ Vt)
{
    const int tile = blockIdx.x, b = blockIdx.y, tid = threadIdx.x;
    {
        const int row = tid >> 3, c = tid & 7;
        const float* src = K + ((size_t)(b * S_LEN + tile * 32 + row)) * 64 + c * 8;
        const f32x4 a = *(const f32x4*)src;
        const f32x4 d = *(const f32x4*)(src + 4);
        short8 w;
        w[0]=(short)f2bf(a[0]); w[1]=(short)f2bf(a[1]); w[2]=(short)f2bf(a[2]); w[3]=(short)f2bf(a[3]);
        w[4]=(short)f2bf(d[0]); w[5]=(short)f2bf(d[1]); w[6]=(short)f2bf(d[2]); w[7]=(short)f2bf(d[3]);
        *(short8*)(Kt + ((size_t)(b * NTILE + tile)) * 2048 + row * 64 + c * 8) = w;
    }
    {
        const int d = tid & 63, kg = tid >> 6;
        short8 w;
        #pragma unroll
        for (int j = 0; j < 8; ++j)
            w[j] = (short)f2bf(V[((size_t)(b * S_LEN + tile * 32 + kg * 8 + j)) * 64 + d]);
        *(short8*)(Vt + ((size_t)(b * NTILE + tile)) * 2048 + d * 32 + kg * 8) = w;
    }
}

// Split-KV flash kernel: 1 wave, 16 q-rows, kv tiles [16c, min(16c+16, nkv))
__global__ __launch_bounds__(64, 3)
void attn_fa3(const float* __restrict__ Q, const float* __restrict__ M,
              const ushort_t* __restrict__ Kt, const ushort_t* __restrict__ Vt,
              unsigned* __restrict__ Opu, float* __restrict__ Pm, float* __restrict__ Pll,
              float* __restrict__ O)
{
    const int x = blockIdx.x, b = blockIdx.y;    // x in [0,1152)
    // job map: v = #chunks segment; tq tile; c chunk
    int v = 1;
    #pragma unroll
    for (int vv = 1; vv < 8; ++vv) v += (x >= 16 * vv * (vv + 1)) ? 1 : 0;
    const int y  = x - 16 * v * (v - 1);
    const int q  = y / v;
    const int c  = y - q * v;
    const int tq = 32 * (v - 1) + q;

    const int nkv = (tq + 2) >> 1;
    const int t0  = 16 * c;
    const int t1  = (t0 + 16 < nkv) ? t0 + 16 : nkv;
    const int qbase = tq * 16;

    const int lane = threadIdx.x, l15 = lane & 15, g = lane >> 4;

    __shared__ __attribute__((aligned(16))) ushort_t Pl[16 * 32];

    // Q as B-fragment (n = l15 = q row, k = g*8+j), scale+1/ln2 folded
    const float* Qrow = Q + ((size_t)(b * S_LEN + qbase + l15)) * 64 + g * 8;
    short8 qf0, qf1;
    #pragma unroll
    for (int j = 0; j < 8; ++j) {
        qf0[j] = (short)f2bf(Qrow[j]      * QSCALE);
        qf1[j] = (short)f2bf(Qrow[32 + j] * QSCALE);
    }

    const char*  ktile = (const char*)Kt + (size_t)b * (NTILE * 4096) + l15 * 128 + g * 16;
    const char*  vtile = (const char*)Vt + (size_t)b * (NTILE * 4096) + l15 * 64  + g * 16;
    const float* Mb    = M + (size_t)b * S_LEN + 4 * g;

    f32x4 acc[4];
    #pragma unroll
    for (int dt = 0; dt < 4; ++dt) acc[dt] = (f32x4){0.f, 0.f, 0.f, 0.f};
    float mx = -3.0e38f, lsum = 0.f;

    short8 kA0,kA1,kA2,kA3, vA0,vA1,vA2,vA3, kB0,kB1,kB2,kB3, vB0,vB1,vB2,vB3;
    f32x4 mA0, mA1, mB0, mB1;

#define LOADSET(SS, tt) do { \
    const char* kp_ = ktile + (size_t)(tt) * 4096; \
    k##SS##0 = *(const short8*)(kp_); \
    k##SS##1 = *(const short8*)(kp_ + 64); \
    k##SS##2 = *(const short8*)(kp_ + 2048); \
    k##SS##3 = *(const short8*)(kp_ + 2048 + 64); \
    const char* vp_ = vtile + (size_t)(tt) * 4096; \
    v##SS##0 = *(const short8*)(vp_); \
    v##SS##1 = *(const short8*)(vp_ + 1024); \
    v##SS##2 = *(const short8*)(vp_ + 2048); \
    v##SS##3 = *(const short8*)(vp_ + 3072); \
    m##SS##0 = *(const f32x4*)(Mb + (tt) * 32); \
    m##SS##1 = *(const f32x4*)(Mb + (tt) * 32 + 16); \
} while (0)

#define COMPUTE(SS, tt) do { \
    const f32x4 z_ = (f32x4){0.f, 0.f, 0.f, 0.f}; \
    f32x4 st0 = __builtin_amdgcn_mfma_f32_16x16x32_bf16(k##SS##0, qf0, z_, 0, 0, 0); \
    st0 = __builtin_amdgcn_mfma_f32_16x16x32_bf16(k##SS##1, qf1, st0, 0, 0, 0); \
    f32x4 st1 = __builtin_amdgcn_mfma_f32_16x16x32_bf16(k##SS##2, qf0, z_, 0, 0, 0); \
    st1 = __builtin_amdgcn_mfma_f32_16x16x32_bf16(k##SS##3, qf1, st1, 0, 0, 0); \
    _Pragma("unroll") \
    for (int r = 0; r < 4; ++r) { \
        st0[r] -= (1.0f - m##SS##0[r]) * BIGF; \
        st1[r] -= (1.0f - m##SS##1[r]) * BIGF; \
    } \
    if ((tt) == nkv - 1) { \
        const int qg = qbase + l15 - (tt) * 32 - 4 * g; \
        _Pragma("unroll") \
        for (int r = 0; r < 4; ++r) { \
            if (r > qg)      st0[r] -= BIGF; \
            if (16 + r > qg) st1[r] -= BIGF; \
        } \
    } \
    float tm = fmaxf(fmaxf(fmaxf(st0[0], st0[1]), fmaxf(st0[2], st0[3])), \
                     fmaxf(fmaxf(st1[0], st1[1]), fmaxf(st1[2], st1[3]))); \
    tm = fmaxf(tm, __shfl_xor(tm, 16)); \
    tm = fmaxf(tm, __shfl_xor(tm, 32)); \
    if (__any(tm > mx + 8.0f)) { \
        const float mnew = fmaxf(mx, tm); \
        const float al   = exp2f(mx - mnew); \
        const float a0 = __shfl(al, 4 * g + 0); \
        const float a1 = __shfl(al, 4 * g + 1); \
        const float a2 = __shfl(al, 4 * g + 2); \
        const float a3 = __shfl(al, 4 * g + 3); \
        _Pragma("unroll") \
        for (int dt = 0; dt < 4; ++dt) { \
            acc[dt][0] *= a0; acc[dt][1] *= a1; \
            acc[dt][2] *= a2; acc[dt][3] *= a3; \
        } \
        lsum *= al; \
        mx = mnew; \
    } \
    float p0[4], p1[4]; \
    _Pragma("unroll") \
    for (int r = 0; r < 4; ++r) { \
        p0[r] = exp2f(st0[r] - mx); \
        p1[r] = exp2f(st1[r] - mx); \
    } \
    float rs = ((p0[0] + p0[1]) + (p0[2] + p0[3])) \
             + ((p1[0] + p1[1]) + (p1[2] + p1[3])); \
    rs += __shfl_xor(rs, 16); \
    rs += __shfl_xor(rs, 32); \
    lsum += rs; \
    unsigned c00, c01, c10, c11; \
    __asm__("v_cvt_pk_bf16_f32 %0, %1, %2" : "=v"(c00) : "v"(p0[0]), "v"(p0[1])); \
    __asm__("v_cvt_pk_bf16_f32 %0, %1, %2" : "=v"(c01) : "v"(p0[2]), "v"(p0[3])); \
    __asm__("v_cvt_pk_bf16_f32 %0, %1, %2" : "=v"(c10) : "v"(p1[0]), "v"(p1[1])); \
    __asm__("v_cvt_pk_bf16_f32 %0, %1, %2" : "=v"(c11) : "v"(p1[2]), "v"(p1[3])); \
    *(uint2v*)&Pl[l15 * 32 + 4 * g]      = (uint2v){c00, c01}; \
    *(uint2v*)&Pl[l15 * 32 + 16 + 4 * g] = (uint2v){c10, c11}; \
    __asm__ volatile("s_waitcnt lgkmcnt(0)" ::: "memory"); \
    __builtin_amdgcn_sched_barrier(0); \
    short8 pf = *(const short8*)&Pl[l15 * 32 + g * 8]; \
    acc[0] = __builtin_amdgcn_mfma_f32_16x16x32_bf16(pf, v##SS##0, acc[0], 0, 0, 0); \
    acc[1] = __builtin_amdgcn_mfma_f32_16x16x32_bf16(pf, v##SS##1, acc[1], 0, 0, 0); \
    acc[2] = __builtin_amdgcn_mfma_f32_16x16x32_bf16(pf, v##SS##2, acc[2], 0, 0, 0); \
    acc[3] = __builtin_amdgcn_mfma_f32_16x16x32_bf16(pf, v##SS##3, acc[3], 0, 0, 0); \
} while (0)

    int t = t0;
    LOADSET(A, t);
    for (;;) {
        if (t + 1 < t1) {
            LOADSET(B, t + 1);
            COMPUTE(A, t);
            ++t;
        } else { COMPUTE(A, t); break; }
        if (t + 1 < t1) {
            LOADSET(A, t + 1);
            COMPUTE(B, t);
            ++t;
        } else { COMPUTE(B, t); break; }
    }
#undef LOADSET
#undef COMPUTE

    if (v == 1) {
        // single chunk (tq < 32): write final O
        const float il0 = 1.0f / __shfl(lsum, 4 * g + 0);
        const float il1 = 1.0f / __shfl(lsum, 4 * g + 1);
        const float il2 = 1.0f / __shfl(lsum, 4 * g + 2);
        const float il3 = 1.0f / __shfl(lsum, 4 * g + 3);
        float* Ob = O + ((size_t)(b * S_LEN + qbase)) * 64;
        #pragma unroll
        for (int dt = 0; dt < 4; ++dt) {
            Ob[(4 * g + 0) * 64 + 16 * dt + l15] = acc[dt][0] * il0;
            Ob[(4 * g + 1) * 64 + 16 * dt + l15] = acc[dt][1] * il1;
            Ob[(4 * g + 2) * 64 + 16 * dt + l15] = acc[dt][2] * il2;
            Ob[(4 * g + 3) * 64 + 16 * dt + l15] = acc[dt][3] * il3;
        }
    } else {
        // partial: bf16 O pairs [d=64][qpair=8], coalesced uint2 stores
        const int slot = b * 1120 + (x - 32);
        unsigned* Os = Opu + (size_t)slot * 512;
        #pragma unroll
        for (int dt = 0; dt < 4; ++dt) {
            unsigned plo, phi;
            __asm__("v_cvt_pk_bf16_f32 %0, %1, %2" : "=v"(plo) : "v"(acc[dt][0]), "v"(acc[dt][1]));
            __asm__("v_cvt_pk_bf16_f32 %0, %1, %2" : "=v"(phi) : "v"(acc[dt][2]), "v"(acc[dt][3]));
            *(uint2v*)&Os[(16 * dt + l15) * 8 + g * 2] = (uint2v){plo, phi};
        }
        if (g == 0) {
            Pm[slot * 16 + l15]  = mx;
            Pll[slot * 16 + l15] = lsum;
        }
    }
}

// Merge partials for tq in [32, 256): up to 8 chunks
__global__ __launch_bounds__(256)
void combine3(const unsigned* __restrict__ Opu, const float* __restrict__ Pm,
              const float* __restrict__ Pll, float* __restrict__ O)
{
    const int tq = 32 + blockIdx.x, b = blockIdx.y;
    const int tid = threadIdx.x, rg = tid >> 6, d = tid & 63;   // rows 4rg..4rg+3
    const int v = (tq + 32) >> 5;
    const int base_x = 16 * v * (v - 1) + (tq - 32 * (v - 1)) * v;
    const int sbase = b * 1120 + base_x - 32;

    float ms[4] = {-3.0e38f, -3.0e38f, -3.0e38f, -3.0e38f};
    for (int cc = 0; cc < v; ++cc) {
        #pragma unroll
        for (int j = 0; j < 4; ++j)
            ms[j] = fmaxf(ms[j], Pm[(sbase + cc) * 16 + 4 * rg + j]);
    }
    float l[4] = {0.f, 0.f, 0.f, 0.f};
    float a[4] = {0.f, 0.f, 0.f, 0.f};
    for (int cc = 0; cc < v; ++cc) {
        float w[4];
        #pragma unroll
        for (int j = 0; j < 4; ++j) {
            w[j] = exp2f(Pm[(sbase + cc) * 16 + 4 * rg + j] - ms[j]);
            l[j] += w[j] * Pll[(sbase + cc) * 16 + 4 * rg + j];
        }
        const uint2v pu = *(const uint2v*)&Opu[(size_t)(sbase + cc) * 512 + d * 8 + rg * 2];
        a[0] += w[0] * bflo(pu[0]);
        a[1] += w[1] * bfhi(pu[0]);
        a[2] += w[2] * bflo(pu[1]);
        a[3] += w[3] * bfhi(pu[1]);
    }
    float* Ob = O + ((size_t)(b * S_LEN + tq * 16 + 4 * rg)) * 64 + d;
    #pragma unroll
    for (int j = 0; j < 4; ++j)
        Ob[(size_t)j * 64] = a[j] / l[j];
}

// =================== tier-3 fallback (no ws) ===================

__global__ __launch_bounds__(256)
void attn_fwd_fb(const float* __restrict__ Q, const float* __restrict__ K,
                 const float* __restrict__ V, const float* __restrict__ M,
                 float* __restrict__ O)
{
    const int tile  = blockIdx.x;
    const int b     = blockIdx.y;
    const int qbase = tile * 64;
    const int tid   = threadIdx.x;
    const int wave  = tid >> 6;
    const int lane  = tid & 63;
    const int l15   = lane & 15;
    const int g     = lane >> 4;

    __shared__ __attribute__((aligned(16))) unsigned short Klds[32 * 64];
    __shared__ __attribute__((aligned(16))) unsigned short Vtlds[64 * 40];
    __shared__ __attribute__((aligned(16))) unsigned short Plds[4][16 * 40];

    const float* Qb = Q + ((size_t)b * S_LEN + qbase) * 64;
    const float* Kb = K + (size_t)b * S_LEN * 64;
    const float* Vb = V + (size_t)b * S_LEN * 64;
    const float* Mb = M + (size_t)b * S_LEN;

    const int qrow = 16 * wave + l15;
    short8 qf[2];
    #pragma unroll
    for (int dc = 0; dc < 2; ++dc) {
        const float* src = Qb + (size_t)qrow * 64 + dc * 32 + g * 8;
        #pragma unroll
        for (int j = 0; j < 8; ++j) qf[dc][j] = (short)f2bf(src[j] * 0.125f);
    }

    f32x4 acc[4];
    #pragma unroll
    for (int dt = 0; dt < 4; ++dt) acc[dt] = (f32x4){0.f, 0.f, 0.f, 0.f};
    float mrow[4], lrow[4];
    #pragma unroll
    for (int r = 0; r < 4; ++r) { mrow[r] = -1e30f; lrow[r] = 0.f; }

    const int q_max_wave = qbase + 16 * wave + 15;
    const int nkv = (qbase + 64) / 32;

    for (int it = 0; it < nkv; ++it) {
        const int kv = it * 32;
        __syncthreads();
        {
            const int k = tid >> 3, c = tid & 7;
            const float* src = Kb + (size_t)(kv + k) * 64 + c * 8;
            short8 t8;
            #pragma unroll
            for (int j = 0; j < 8; ++j) t8[j] = (short)f2bf(src[j]);
            const int byte = k * 128 + ((c * 16) ^ ((k & 7) << 4));
            *(short8*)((char*)Klds + byte) = t8;
        }
        {
            const int k = tid & 31, dch = tid >> 5;
            const float* src = Vb + (size_t)(kv + k) * 64 + dch * 8;
            #pragma unroll
            for (int j = 0; j < 8; ++j)
                Vtlds[(dch * 8 + j) * 40 + k] = f2bf(src[j]);
        }
        __syncthreads();

        if (kv > q_max_wave) continue;

        f32x4 s[2];
        s[0] = (f32x4){0.f,0.f,0.f,0.f};
        s[1] = (f32x4){0.f,0.f,0.f,0.f};
        #pragma unroll
        for (int kt = 0; kt < 2; ++kt) {
            const int krow = 16 * kt + l15;
            #pragma unroll
            for (int dc = 0; dc < 2; ++dc) {
                const int byte = krow * 128 + ((dc * 64 + g * 16) ^ ((krow & 7) << 4));
                short8 kf = *(const short8*)((const char*)Klds + byte);
                s[kt] = __builtin_amdgcn_mfma_f32_16x16x32_bf16(qf[dc], kf, s[kt], 0, 0, 0);
            }
        }

        float mk0 = Mb[kv + l15];
        float mk1 = Mb[kv + 16 + l15];
        #pragma unroll
        for (int kt = 0; kt < 2; ++kt) {
            const int gk = kv + 16 * kt + l15;
            const float madd = (1.0f - (kt ? mk1 : mk0)) * BIGNEG;
            #pragma unroll
            for (int r = 0; r < 4; ++r) {
                const int gq = qbase + 16 * wave + 4 * g + r;
                float vv = s[kt][r] - madd;
                if (gk > gq) vv -= BIGNEG;
                s[kt][r] = vv;
            }
        }

        float pexp[2][4], alpha[4];
        #pragma unroll
        for (int r = 0; r < 4; ++r) {
            float tm = fmaxf(s[0][r], s[1][r]);
            #pragma unroll
            for (int off = 8; off >= 1; off >>= 1)
                tm = fmaxf(tm, __shfl_xor(tm, off, 64));
            const float mnew = fmaxf(mrow[r], tm);
            const float a  = __expf(mrow[r] - mnew);
            const float p0 = __expf(s[0][r] - mnew);
            const float p1 = __expf(s[1][r] - mnew);
            float rs = p0 + p1;
            #pragma unroll
            for (int off = 8; off >= 1; off >>= 1)
                rs += __shfl_xor(rs, off, 64);
            lrow[r] = lrow[r] * a + rs;
            mrow[r] = mnew;
            alpha[r] = a;
            pexp[0][r] = p0; pexp[1][r] = p1;
        }

        #pragma unroll
        for (int dt = 0; dt < 4; ++dt)
            #pragma unroll
            for (int r = 0; r < 4; ++r)
                acc[dt][r] *= alpha[r];

        unsigned short* P = Plds[wave];
        #pragma unroll
        for (int kt = 0; kt < 2; ++kt)
            #pragma unroll
            for (int r = 0; r < 4; ++r)
                P[(4 * g + r) * 40 + 16 * kt + l15] = f2bf(pexp[kt][r]);

        __asm__ volatile("s_waitcnt lgkmcnt(0)" ::: "memory");

        short8 pf = *(const short8*)((const char*)P + (l15 * 40 + g * 8) * 2);
        #pragma unroll
        for (int dt = 0; dt < 4; ++dt) {
            short8 vf = *(const short8*)((const char*)Vtlds + ((dt * 16 + l15) * 40 + g * 8) * 2);
            acc[dt] = __builtin_amdgcn_mfma_f32_16x16x32_bf16(pf, vf, acc[dt], 0, 0, 0);
        }
    }

    float* Ob = O + ((size_t)b * S_LEN + qbase) * 64;
    #pragma unroll
    for (int r = 0; r < 4; ++r) {
        const float inv = 1.0f / lrow[r];
        const int row = 16 * wave + 4 * g + r;
        #pragma unroll
        for (int dt = 0; dt < 4; ++dt)
            Ob[(size_t)row * 64 + dt * 16 + l15] = acc[dt][r] * inv;
    }
}

extern "C" void kernel_launch(void* const* d_in, const int* in_sizes, int n_in,
                              void* d_out, int out_size, void* d_ws, size_t ws_size,
                              hipStream_t stream) {
    const float* Q = (const float*)d_in[0];
    const float* K = (const float*)d_in[1];
    const float* V = (const float*)d_in[2];
    const float* M = (const float*)d_in[3];
    float* O = (float*)d_out;

    if (ws_size >= (size_t)WS3_NEEDED) {
        ushort_t* Kt = (ushort_t*)((char*)d_ws + KT2_OFF);
        ushort_t* Vt = (ushort_t*)((char*)d_ws + VT2_OFF);
        unsigned* Op = (unsigned*)((char*)d_ws + OP_OFF);
        float*    Pm = (float*)((char*)d_ws + PM_OFF);
        float*    Pll= (float*)((char*)d_ws + PLS_OFF);
        prep2<<<dim3(NTILE, N_B), 256, 0, stream>>>(K, V, Kt, Vt);
        attn_fa3<<<dim3(1152, N_B), 64, 0, stream>>>(Q, M, Kt, Vt, Op, Pm, Pll, O);
        combine3<<<dim3(224, N_B), 256, 0, stream>>>(Op, Pm, Pll, O);
    } else {
        dim3 grid(S_LEN / 64, N_B);
        attn_fwd_fb<<<grid, 256, 0, stream>>>(Q, K, V, M, O);
    }
}